// Round 7
// baseline (202.946 us; speedup 1.0000x reference)
//
#include <hip/hip_runtime.h>
#include <hip/hip_bf16.h>

typedef unsigned short u16;
typedef unsigned int   u32;
typedef __attribute__((ext_vector_type(8))) short bf16x8;
typedef __attribute__((ext_vector_type(4))) float f32x4;

#define GPB 4   // graphs per block; M = 64 rows (m-tile == graph)

__constant__ int ADJ_DEG[16] = {3,4,4,3, 4,5,5,4, 4,5,5,4, 3,4,4,3};
__constant__ int ADJ_SRC[16][5] = {
  {0,1,4,0,0},   {1,0,2,5,0},   {2,1,3,6,0},   {3,2,7,0,0},
  {4,5,0,8,0},   {5,4,6,1,9},   {6,5,7,2,10},  {7,6,3,11,0},
  {8,9,4,12,0},  {9,8,10,5,13}, {10,9,11,6,14},{11,10,7,15,0},
  {12,13,8,0,0}, {13,12,14,9,0},{14,13,15,10,0},{15,14,11,0,0}
};

struct SMem {
  char hA[64*512];      // bf16 [64 rows][256 cols], XOR-swizzled; o64 fp32 [64][68] after layer2
  char hBT[4*256*32];   // bf16 X^T [g][c 0..255][s 0..15], 32B rows, swizzled; w_in_s (4KB) during pre
  union {
    struct { float h0f[64][17]; float w_in_s[16][64]; } pre;          // 8448 B
    struct { float asd[64][4][2]; char ptb[16*32*16]; } post;         // 2048 + 8192
    struct { float grs[4][64]; float z1[4][128]; float red[2][8][2]; } mlp;
  } u;
};  // 32768 + 32768 + 10240 = 75776 B -> 2 blocks/CU

__device__ __forceinline__ int swz(int row, int b) { return (row << 9) + (b ^ ((row & 7) << 4)); }
// X^T byte address: graph g, column c (0..255), byte-in-row b (0..31)
__device__ __forceinline__ int xswz(int g, int c, int b) {
  return (g << 13) + (c << 5) + (b ^ (((c >> 2) & 3) << 3));
}
__device__ __forceinline__ u32 f2bf1(float x) {           // RNE float->bf16 bits (prep)
  u32 u = __float_as_uint(x);
  return (u + 0x7fffu + ((u >> 16) & 1u)) >> 16;
}
__device__ __forceinline__ u32 pk2(float a, float b) {    // packed cvt (v_cvt_pk_bf16_f32)
  __hip_bfloat162 h2 = __float22bfloat162_rn(make_float2(a, b));
  union { __hip_bfloat162 h; u32 u; } cv; cv.h = h2; return cv.u;
}

// ---- GEMM x = hA @ W, W frags (N=272: 256 cols + 8 fused att cols + pad) from L2.
// mfma(X as A, W as B): lane holds D[node s = lg*4+reg][col c = tile*16 + l15].
// wave w: m-tiles (graphs) mt0, mt0+1; n-tiles nt0..nt0+3 (+ att tile if nt0==0).
template<int KC>
__device__ __forceinline__ void gemm_att(SMem& sm, const uint4* __restrict__ wsrc, int t) {
  const int lane = t & 63, w = t >> 6;
  const int mt0 = (w >> 2) * 2;
  const int nt0 = (w & 3) * 4;
  const int l15 = lane & 15, lg = lane >> 4;
  const bool hasAtt = (nt0 == 0);

  f32x4 acc[2][4]; f32x4 accA[2];
#pragma unroll
  for (int rt = 0; rt < 2; ++rt) {
    accA[rt] = (f32x4){0.f, 0.f, 0.f, 0.f};
#pragma unroll
    for (int ct = 0; ct < 4; ++ct) acc[rt][ct] = (f32x4){0.f, 0.f, 0.f, 0.f};
  }

#pragma unroll
  for (int kc = 0; kc < KC; ++kc) {
    uint4 bw[4];
#pragma unroll
    for (int ct = 0; ct < 4; ++ct)
      bw[ct] = wsrc[(kc*17 + nt0 + ct)*64 + lane];
    uint4 ba;
    if (hasAtt) ba = wsrc[(kc*17 + 16)*64 + lane];
    bf16x8 a[2];
#pragma unroll
    for (int rt = 0; rt < 2; ++rt)
      a[rt] = *(const bf16x8*)(sm.hA + swz((mt0 + rt)*16 + l15, kc*64 + lg*16));
#pragma unroll
    for (int rt = 0; rt < 2; ++rt) {
#pragma unroll
      for (int ct = 0; ct < 4; ++ct)
        acc[rt][ct] = __builtin_amdgcn_mfma_f32_16x16x32_bf16(a[rt], *(const bf16x8*)&bw[ct], acc[rt][ct], 0, 0, 0);
      if (hasAtt)
        accA[rt] = __builtin_amdgcn_mfma_f32_16x16x32_bf16(a[rt], *(const bf16x8*)&ba, accA[rt], 0, 0, 0);
    }
  }

  // X^T epilogue: per (rt, ct), lane holds 4 nodes (s = lg*4..+3) of col c
#pragma unroll
  for (int rt = 0; rt < 2; ++rt)
#pragma unroll
    for (int ct = 0; ct < 4; ++ct) {
      const int c = (nt0 + ct)*16 + l15;
      uint2 o;
      o.x = pk2(acc[rt][ct][0], acc[rt][ct][1]);
      o.y = pk2(acc[rt][ct][2], acc[rt][ct][3]);
      *(uint2*)(sm.hBT + xswz(mt0 + rt, c, lg*8)) = o;
    }
  // attention columns: l15<4 -> a_s head l15; l15 in 4..7 -> a_d head l15-4
  if (hasAtt && l15 < 8) {
    const int h = l15 & 3, sd = l15 >> 2;
#pragma unroll
    for (int rt = 0; rt < 2; ++rt)
#pragma unroll
      for (int reg = 0; reg < 4; ++reg)
        sm.u.post.asd[(mt0 + rt)*16 + lg*4 + reg][h][sd] = accA[rt][reg];
  }
}

// ---- softmax over incoming edges; scatter into P^T B-fragments (bf16, K=32 zero-padded) ----
__device__ __forceinline__ void softmax_pt(SMem& sm, int t) {
  if (t < 256) {
    const int g = t >> 6, d = (t >> 2) & 15, h = t & 3;
    const int deg = ADJ_DEG[d];
    const float advl = sm.u.post.asd[(g << 4) + d][h][1];
    float al[5]; int srcs[5];
    float m = -1e30f;
#pragma unroll
    for (int k = 0; k < 5; ++k) {
      srcs[k] = (k < deg) ? ADJ_SRC[d][k] : 99;
      float v = 0.f;
      if (k < deg) {
        v = sm.u.post.asd[(g << 4) + ADJ_SRC[d][k]][h][0] + advl;
        v = (v > 0.f) ? v : 0.2f * v;          // leaky_relu 0.2
        m = fmaxf(m, v);
      }
      al[k] = v;
    }
    float ssum = 0.f;
#pragma unroll
    for (int k = 0; k < 5; ++k)
      if (k < deg) { const float e = __expf(al[k] - m); al[k] = e; ssum += e; }
    const float inv = 1.f / ssum;
    float p[16];
#pragma unroll
    for (int s = 0; s < 16; ++s) {
      float v = 0.f;
#pragma unroll
      for (int k = 0; k < 5; ++k) v = (srcs[k] == s) ? al[k] * inv : v;
      p[s] = v;
    }
    uint4 lo, hi;
    lo.x = pk2(p[0],p[1]);   lo.y = pk2(p[2],p[3]);   lo.z = pk2(p[4],p[5]);   lo.w = pk2(p[6],p[7]);
    hi.x = pk2(p[8],p[9]);   hi.y = pk2(p[10],p[11]); hi.z = pk2(p[12],p[13]); hi.w = pk2(p[14],p[15]);
    char* pt = sm.u.post.ptb + (((g*4 + h)*32 + d) << 4);
    *(uint4*)pt = lo;
    *(uint4*)(pt + 256) = hi;
  }
}

// ---- aggregation via MFMA: D = X^T @ P^T; lane holds [c = ct*16+lg*4+reg][d = l15] ----
template<int MODE>   // 0: concat+bias+relu -> hA bf16; 1: mean heads + bias -> o64 fp32 (hA region)
__device__ __forceinline__ void aggregate_mfma(SMem& sm, const float* __restrict__ bias, int t) {
  const int lane = t & 63, w = t >> 6;
  const int g = w >> 1, l15 = lane & 15, lg = lane >> 4;
  const bf16x8 zero8 = {0,0,0,0,0,0,0,0};

  if (MODE == 0) {
#pragma unroll
    for (int hp = 0; hp < 2; ++hp) {
      const int h = (w & 1)*2 + hp;
      bf16x8 b = zero8;
      if (lane < 32) b = *(const bf16x8*)(sm.u.post.ptb + (((g*4 + h)*32 + lane) << 4));
#pragma unroll
      for (int ct = 0; ct < 4; ++ct) {
        bf16x8 a = zero8;
        if (lane < 32) {
          const int c = h*64 + ct*16 + l15;
          union { uint2 u2[2]; bf16x8 v; } cv;
          cv.u2[0] = *(const uint2*)(sm.hBT + xswz(g, c, lg*16));
          cv.u2[1] = *(const uint2*)(sm.hBT + xswz(g, c, lg*16 + 8));
          a = cv.v;
        }
        f32x4 acc = {0.f, 0.f, 0.f, 0.f};
        acc = __builtin_amdgcn_mfma_f32_16x16x32_bf16(a, b, acc, 0, 0, 0);
        const int c0 = h*64 + ct*16 + lg*4;
        const float4 bv = *(const float4*)(bias + c0);
        uint2 o;
        o.x = pk2(fmaxf(acc[0] + bv.x, 0.f), fmaxf(acc[1] + bv.y, 0.f));
        o.y = pk2(fmaxf(acc[2] + bv.z, 0.f), fmaxf(acc[3] + bv.w, 0.f));
        *(uint2*)(sm.hA + swz(g*16 + l15, 2*c0)) = o;
      }
    }
  } else {
#pragma unroll
    for (int cp = 0; cp < 2; ++cp) {
      const int ct = (w & 1)*2 + cp;
      f32x4 acc = {0.f, 0.f, 0.f, 0.f};
#pragma unroll
      for (int h = 0; h < 4; ++h) {          // chain heads (sum over heads)
        bf16x8 a = zero8, b = zero8;
        if (lane < 32) {
          b = *(const bf16x8*)(sm.u.post.ptb + (((g*4 + h)*32 + lane) << 4));
          const int c = h*64 + ct*16 + l15;
          union { uint2 u2[2]; bf16x8 v; } cv;
          cv.u2[0] = *(const uint2*)(sm.hBT + xswz(g, c, lg*16));
          cv.u2[1] = *(const uint2*)(sm.hBT + xswz(g, c, lg*16 + 8));
          a = cv.v;
        }
        acc = __builtin_amdgcn_mfma_f32_16x16x32_bf16(a, b, acc, 0, 0, 0);
      }
      float (*o64)[68] = (float (*)[68])sm.hA;
      const int ci = ct*16 + lg*4;
      const float4 bv = *(const float4*)(bias + ci);
      float4 ov;
      ov.x = fmaf(0.25f, acc[0], bv.x);
      ov.y = fmaf(0.25f, acc[1], bv.y);
      ov.z = fmaf(0.25f, acc[2], bv.z);
      ov.w = fmaf(0.25f, acc[3], bv.w);
      *(float4*)&o64[(g << 4) + l15][ci] = ov;
    }
  }
}

extern "C" __global__ void __launch_bounds__(512, 4)
gat_main(const float* __restrict__ xg,
         const float* __restrict__ w_in, const float* __restrict__ b_in,
         const float* __restrict__ bias0, const float* __restrict__ bias1,
         const float* __restrict__ bias2,
         const uint4* __restrict__ wq0, const uint4* __restrict__ wq1,
         const uint4* __restrict__ wq2,
         const float* __restrict__ mw1, const float* __restrict__ mb1,
         const float* __restrict__ g1, const float* __restrict__ be1,
         const u32* __restrict__ mwb2, const float* __restrict__ mb2,
         const float* __restrict__ g2, const float* __restrict__ be2,
         float* __restrict__ out, int Btot)
{
  __shared__ SMem sm;
  const int t = threadIdx.x;
  const int b0 = blockIdx.x * GPB;
  if (b0 >= Btot) return;

  // ---- load x (transpose to node-major) + stage w_in into hBT head ----
  if (t < 256) {
    const float4 v = *(const float4*)(xg + (size_t)b0*256 + 4*t);
    const int flat = 4*t, g = flat >> 8, rem = flat & 255;
    const int c = rem >> 4, n0 = rem & 15;
    sm.u.pre.h0f[(g << 4) + n0 + 0][c] = v.x;
    sm.u.pre.h0f[(g << 4) + n0 + 1][c] = v.y;
    sm.u.pre.h0f[(g << 4) + n0 + 2][c] = v.z;
    sm.u.pre.h0f[(g << 4) + n0 + 3][c] = v.w;
    ((float4*)sm.u.pre.w_in_s)[t] = ((const float4*)w_in)[t];
  }
  __syncthreads();

  // ---- in-proj: h1 = relu(h0 @ w_in + b_in) -> hA bf16 swizzled (64 cols) ----
  {
    const int r = t >> 3, q = t & 7;
    const float4 bA = *(const float4*)(b_in + 8*q);
    const float4 bB = *(const float4*)(b_in + 8*q + 4);
    float a0=bA.x,a1=bA.y,a2=bA.z,a3=bA.w,a4=bB.x,a5=bB.y,a6=bB.z,a7=bB.w;
#pragma unroll
    for (int k = 0; k < 16; ++k) {
      const float hv = sm.u.pre.h0f[r][k];
      const float4 wA = *(const float4*)(&sm.u.pre.w_in_s[k][8*q]);
      const float4 wB = *(const float4*)(&sm.u.pre.w_in_s[k][8*q + 4]);
      a0 = fmaf(hv, wA.x, a0); a1 = fmaf(hv, wA.y, a1);
      a2 = fmaf(hv, wA.z, a2); a3 = fmaf(hv, wA.w, a3);
      a4 = fmaf(hv, wB.x, a4); a5 = fmaf(hv, wB.y, a5);
      a6 = fmaf(hv, wB.z, a6); a7 = fmaf(hv, wB.w, a7);
    }
    uint4 uo;
    uo.x = pk2(fmaxf(a0,0.f), fmaxf(a1,0.f));
    uo.y = pk2(fmaxf(a2,0.f), fmaxf(a3,0.f));
    uo.z = pk2(fmaxf(a4,0.f), fmaxf(a5,0.f));
    uo.w = pk2(fmaxf(a6,0.f), fmaxf(a7,0.f));
    *(uint4*)(sm.hA + swz(r, 16*q)) = uo;
  }
  __syncthreads();

  // ---- GAT layer 0 (K=64) ----
  gemm_att<2>(sm, wq0, t);         __syncthreads();
  softmax_pt(sm, t);               __syncthreads();
  aggregate_mfma<0>(sm, bias0, t); __syncthreads();

  // ---- GAT layer 1 (K=256) ----
  gemm_att<8>(sm, wq1, t);         __syncthreads();
  softmax_pt(sm, t);               __syncthreads();
  aggregate_mfma<0>(sm, bias1, t); __syncthreads();

  // ---- GAT layer 2 (K=256, mean over heads) ----
  gemm_att<8>(sm, wq2, t);         __syncthreads();
  softmax_pt(sm, t);               __syncthreads();
  aggregate_mfma<1>(sm, bias2, t); __syncthreads();

  // ---- global mean pool over 16 nodes ----
  if (t < 256) {
    const int g = t >> 6, col = t & 63;
    const float (*o64)[68] = (const float (*)[68])sm.hA;
    float s = 0.f;
#pragma unroll
    for (int r = 0; r < 16; ++r) s += o64[(g << 4) + r][col];
    sm.u.mlp.grs[g][col] = s * (1.f/16.f);
  }
  __syncthreads();

  // ---- MLP1 [64]->[128] (all 512 threads: 4 graphs x 128 outputs) ----
  const int mg = t >> 7, o = t & 127, w = t >> 6;
  float a1v = mb1[o];
#pragma unroll 8
  for (int k = 0; k < 64; ++k) a1v = fmaf(sm.u.mlp.grs[mg][k], mw1[k*128 + o], a1v);
  {
    float su = a1v, sq = a1v*a1v;
#pragma unroll
    for (int off = 32; off >= 1; off >>= 1) { su += __shfl_xor(su, off); sq += __shfl_xor(sq, off); }
    if ((t & 63) == 0) { sm.u.mlp.red[0][w][0] = su; sm.u.mlp.red[0][w][1] = sq; }
  }
  __syncthreads();
  {
    const float mu = (sm.u.mlp.red[0][2*mg][0] + sm.u.mlp.red[0][2*mg+1][0]) * (1.f/128.f);
    const float mq = (sm.u.mlp.red[0][2*mg][1] + sm.u.mlp.red[0][2*mg+1][1]) * (1.f/128.f);
    const float rstd = rsqrtf(mq - mu*mu + 1e-5f);
    sm.u.mlp.z1[mg][o] = fmaxf((a1v - mu)*rstd*g1[o] + be1[o], 0.f);
  }
  __syncthreads();

  // ---- MLP2 [128]->[256], LN, relu, store (each thread: 2 outputs) ----
  {
    const float2 bb2 = *(const float2*)(mb2 + 2*o);
    float c0 = bb2.x, c1 = bb2.y;
#pragma unroll 8
    for (int k = 0; k < 128; ++k) {
      const float zk = sm.u.mlp.z1[mg][k];
      const u32 uw = mwb2[k*128 + o];
      c0 = fmaf(zk, __uint_as_float(uw << 16), c0);
      c1 = fmaf(zk, __uint_as_float(uw & 0xffff0000u), c1);
    }
    float su = c0 + c1, sq = c0*c0 + c1*c1;
#pragma unroll
    for (int off = 32; off >= 1; off >>= 1) { su += __shfl_xor(su, off); sq += __shfl_xor(sq, off); }
    if ((t & 63) == 0) { sm.u.mlp.red[1][w][0] = su; sm.u.mlp.red[1][w][1] = sq; }
    __syncthreads();
    const float mu = (sm.u.mlp.red[1][2*mg][0] + sm.u.mlp.red[1][2*mg+1][0]) * (1.f/256.f);
    const float mq = (sm.u.mlp.red[1][2*mg][1] + sm.u.mlp.red[1][2*mg+1][1]) * (1.f/256.f);
    const float rstd = rsqrtf(mq - mu*mu + 1e-5f);
    const float2 gg2  = *(const float2*)(g2  + 2*o);
    const float2 bbe2 = *(const float2*)(be2 + 2*o);
    float2 ov;
    ov.x = fmaxf((c0 - mu)*rstd*gg2.x + bbe2.x, 0.f);
    ov.y = fmaxf((c1 - mu)*rstd*gg2.y + bbe2.y, 0.f);
    *(float2*)(out + (size_t)(b0 + mg)*256 + 2*o) = ov;
  }
}

// ---- prepass: W0/W1/W2 -> bf16 B-fragment layout with fused attention columns (N-tiles 0..16);
//      mw2 -> bf16 row-major pairs ----
// u16 layout: wf0 [kc2][nt17][lane64][j8] = 17408; wf1 at 17408 (69632); wf2 at 87040 (69632);
//             mw2 bf16 at 156672 (32768). Total 189440 u16.
__global__ void __launch_bounds__(256)
prep_w(const float* __restrict__ w0, const float* __restrict__ as0, const float* __restrict__ ad0,
       const float* __restrict__ w1, const float* __restrict__ as1, const float* __restrict__ ad1,
       const float* __restrict__ w2, const float* __restrict__ as2, const float* __restrict__ ad2,
       const float* __restrict__ mw2, u16* __restrict__ wf) {
  const int f = blockIdx.x*256 + threadIdx.x;
  if (f >= 189440) return;
  if (f >= 156672) { wf[f] = (u16)f2bf1(mw2[f - 156672]); return; }
  const float *W, *as_, *ad_; int local;
  if (f < 17408)      { W = w0; as_ = as0; ad_ = ad0; local = f; }
  else if (f < 87040) { W = w1; as_ = as1; ad_ = ad1; local = f - 17408; }
  else                { W = w2; as_ = as2; ad_ = ad2; local = f - 87040; }
  const int kc = local / 8704;
  const int r  = local - kc*8704;
  const int nt = r >> 9;
  const int lane = (r >> 3) & 63;
  const int j = r & 7;
  const int k = kc*32 + (lane >> 4)*8 + j;
  const int l15 = lane & 15;
  float val;
  if (nt < 16) {
    val = W[k*256 + nt*16 + l15];
  } else if (l15 < 8) {
    const int h = l15 & 3;
    const float* av = (l15 < 4) ? as_ : ad_;
    float s = 0.f;
    for (int c = 0; c < 64; ++c) s = fmaf(W[k*256 + h*64 + c], av[h*64 + c], s);
    val = s;
  } else {
    val = 0.f;
  }
  wf[f] = (u16)f2bf1(val);
}

extern "C" void kernel_launch(void* const* d_in, const int* in_sizes, int n_in,
                              void* d_out, int out_size, void* d_ws, size_t ws_size,
                              hipStream_t stream) {
  (void)n_in; (void)out_size; (void)ws_size;
  const float* xg   = (const float*)d_in[0];
  const float* w_in = (const float*)d_in[1];
  const float* b_in = (const float*)d_in[2];
  const float* w0   = (const float*)d_in[3];
  const float* as0  = (const float*)d_in[4];
  const float* ad0  = (const float*)d_in[5];
  const float* bi0  = (const float*)d_in[6];
  const float* w1   = (const float*)d_in[7];
  const float* as1  = (const float*)d_in[8];
  const float* ad1  = (const float*)d_in[9];
  const float* bi1  = (const float*)d_in[10];
  const float* w2   = (const float*)d_in[11];
  const float* as2  = (const float*)d_in[12];
  const float* ad2  = (const float*)d_in[13];
  const float* bi2  = (const float*)d_in[14];
  const float* mw1  = (const float*)d_in[15];
  const float* mb1  = (const float*)d_in[16];
  const float* g1   = (const float*)d_in[17];
  const float* be1  = (const float*)d_in[18];
  const float* mw2  = (const float*)d_in[19];
  const float* mb2  = (const float*)d_in[20];
  const float* g2   = (const float*)d_in[21];
  const float* be2  = (const float*)d_in[22];
  float* out = (float*)d_out;

  const int Btot = in_sizes[0] / 256;               // 8192
  u16* wf = (u16*)d_ws;                             // 189440 u16 = 370 KB
  const uint4* wq0 = (const uint4*)wf;
  const uint4* wq1 = (const uint4*)(wf + 17408);
  const uint4* wq2 = (const uint4*)(wf + 87040);
  const u32* mwb2  = (const u32*)(wf + 156672);

  hipLaunchKernelGGL(prep_w, dim3(740), dim3(256), 0, stream,
                     w0, as0, ad0, w1, as1, ad1, w2, as2, ad2, mw2, wf);

  const int nblocks = (Btot + GPB - 1) / GPB;       // 2048
  hipLaunchKernelGGL(gat_main, dim3(nblocks), dim3(512), 0, stream,
                     xg, w_in, b_in, bi0, bi1, bi2, wq0, wq1, wq2,
                     mw1, mb1, g1, be1, mwb2, mb2, g2, be2, out, Btot);
}

// Round 9
// 171.360 us; speedup vs baseline: 1.1843x; 1.1843x over previous
//
#include <hip/hip_runtime.h>
#include <hip/hip_bf16.h>

typedef unsigned short u16;
typedef unsigned int   u32;
typedef __attribute__((ext_vector_type(8)))  short bf16x8;
typedef __attribute__((ext_vector_type(16))) float f32x16;

#define GPB 4
#define ZERO16 (f32x16){0.f,0.f,0.f,0.f,0.f,0.f,0.f,0.f,0.f,0.f,0.f,0.f,0.f,0.f,0.f,0.f}
#define MFMA32 __builtin_amdgcn_mfma_f32_32x32x16_bf16

__constant__ int ADJ_DEG[16] = {3,4,4,3, 4,5,5,4, 4,5,5,4, 3,4,4,3};
__constant__ int ADJ_SRC[16][5] = {
  {0,1,4,0,0},   {1,0,2,5,0},   {2,1,3,6,0},   {3,2,7,0,0},
  {4,5,0,8,0},   {5,4,6,1,9},   {6,5,7,2,10},  {7,6,3,11,0},
  {8,9,4,12,0},  {9,8,10,5,13}, {10,9,11,6,14},{11,10,7,15,0},
  {12,13,8,0,0}, {13,12,14,9,0},{14,13,15,10,0},{15,14,11,0,0}
};

struct SMem {
  char hA[64*512];      // bf16 [64 rows][256 cols] row-major, XOR-swizzled; o64 fp32 [64][68] after L2
  char hBT[4*256*32];   // bf16 X^T [g][c][node 0..15], 32B rows, bit4-XOR swizzled
  union {
    struct { float asd[64][8]; char ptb[16*16*32]; } post;              // 2KB + 8KB (per g,h,d)
    struct { float grs[4][64]; float z1[4][128]; float red[2][8][2]; } mlp;
  } u;
};  // ~74 KB -> 2 blocks/CU

__device__ __forceinline__ int swz(int row, int b) { return (row << 9) + (b ^ ((row & 7) << 4)); }
__device__ __forceinline__ int xswz(int g, int c, int b) {
  return (g << 13) + (c << 5) + (b ^ (((c >> 2) & 1) << 4));
}
__device__ __forceinline__ u32 f2bf1(float x) {
  u32 u = __float_as_uint(x);
  return (u + 0x7fffu + ((u >> 16) & 1u)) >> 16;
}
__device__ __forceinline__ u32 pk2(float a, float b) {
  __hip_bfloat162 h2 = __float22bfloat162_rn(make_float2(a, b));
  union { __hip_bfloat162 h; u32 u; } cv; cv.h = h2; return cv.u;
}

// ---- GEMM x = h @ W via 32x32x16; wave w owns n-tile w (32 cols), both m-halves.
// Waves 0-1 also compute fused att tile (nt=8) for m-half w, then wave-local softmax -> ptb.
template<int KS>
__device__ __forceinline__ void gemm32(SMem& sm, const uint4* __restrict__ wsrc, int t) {
  const int lane = t & 63, w = t >> 6;
  const int l31 = lane & 31, hi = lane >> 5;
  const bool hasAtt = (w < 2);

  f32x16 acc0 = ZERO16, acc1 = ZERO16, accA = ZERO16;

#pragma unroll 4
  for (int ks = 0; ks < KS; ++ks) {
    const uint4 bw = wsrc[(ks*9 + w)*64 + lane];
    uint4 ba;
    if (hasAtt) ba = wsrc[(ks*9 + 8)*64 + lane];
    const bf16x8 a0 = *(const bf16x8*)(sm.hA + swz(l31,      ks*32 + hi*16));
    const bf16x8 a1 = *(const bf16x8*)(sm.hA + swz(32 + l31, ks*32 + hi*16));
    acc0 = MFMA32(a0, *(const bf16x8*)&bw, acc0, 0, 0, 0);
    acc1 = MFMA32(a1, *(const bf16x8*)&bw, acc1, 0, 0, 0);
    if (hasAtt) accA = MFMA32((w == 0) ? a0 : a1, *(const bf16x8*)&ba, accA, 0, 0, 0);
  }

  // X^T epilogue: lane = col c, rows r = (reg&3)+8*(reg>>2)+4*hi
  const int c = w*32 + l31;
#pragma unroll
  for (int mh = 0; mh < 2; ++mh) {
    const f32x16 A = mh ? acc1 : acc0;
#pragma unroll
    for (int grp = 0; grp < 4; ++grp) {
      const int g  = mh*2 + (grp >> 1);
      const int n0 = (grp & 1)*8 + hi*4;
      uint2 o;
      o.x = pk2(A[grp*4+0], A[grp*4+1]);
      o.y = pk2(A[grp*4+2], A[grp*4+3]);
      *(uint2*)(sm.hBT + xswz(g, c, n0*2)) = o;
    }
  }

  if (hasAtt) {
    if (l31 < 8) {
#pragma unroll
      for (int grp = 0; grp < 4; ++grp) {
        const int g  = w*2 + (grp >> 1);
        const int n0 = (grp & 1)*8 + hi*4;
#pragma unroll
        for (int i = 0; i < 4; ++i)
          sm.u.post.asd[g*16 + n0 + i][l31] = accA[grp*4+i];
      }
    }
    // wave-local softmax (same-wave LDS ops are in-order; no block barrier needed)
    const int g = w*2 + hi;
    const int h = lane & 3;
#pragma unroll
    for (int dd = 0; dd < 2; ++dd) {
      const int d = ((lane >> 2) & 7) + dd*8;
      const int deg = ADJ_DEG[d];
      const float advl = sm.u.post.asd[g*16 + d][4 + h];
      float al[5]; int srcs[5];
      float m = -1e30f;
#pragma unroll
      for (int k = 0; k < 5; ++k) {
        srcs[k] = (k < deg) ? ADJ_SRC[d][k] : 99;
        float v = 0.f;
        if (k < deg) {
          v = sm.u.post.asd[g*16 + srcs[k]][h] + advl;
          v = (v > 0.f) ? v : 0.2f * v;          // leaky_relu 0.2
          m = fmaxf(m, v);
        }
        al[k] = v;
      }
      float ssum = 0.f;
#pragma unroll
      for (int k = 0; k < 5; ++k)
        if (k < deg) { const float e = __expf(al[k] - m); al[k] = e; ssum += e; }
      const float inv = 1.f / ssum;
      float p[16];
#pragma unroll
      for (int s = 0; s < 16; ++s) {
        float v = 0.f;
#pragma unroll
        for (int k = 0; k < 5; ++k) v = (srcs[k] == s) ? al[k] * inv : v;
        p[s] = v;
      }
      uint4 lo, hh;
      lo.x = pk2(p[0],p[1]);   lo.y = pk2(p[2],p[3]);   lo.z = pk2(p[4],p[5]);   lo.w = pk2(p[6],p[7]);
      hh.x = pk2(p[8],p[9]);   hh.y = pk2(p[10],p[11]); hh.z = pk2(p[12],p[13]); hh.w = pk2(p[14],p[15]);
      char* pt = sm.u.post.ptb + (((g*4 + h)*16 + d) << 5);    // per (g, h, d) row
      *(uint4*)pt = lo;
      *(uint4*)(pt + 16) = hh;
    }
  }
}

// ---- aggregation: D = X^T @ P_h^T via 32x32x16 (dst cols 16-31 zero-padded) ----
template<int MODE>   // 0: concat+bias+relu -> hA; 1: mean heads + bias -> o64 fp32
__device__ __forceinline__ void agg32(SMem& sm, const float* __restrict__ bias, int t) {
  const int lane = t & 63, w = t >> 6;
  const int l31 = lane & 31, hi = lane >> 5;
  const int g = w >> 1;
  const bf16x8 zero8 = {0,0,0,0,0,0,0,0};

  if (MODE == 0) {
#pragma unroll
    for (int i = 0; i < 4; ++i) {
      const int mt = (w & 1)*4 + i;
      const int h = mt >> 1;                      // head owning this 32-col feature tile
      bf16x8 pb = zero8;
      if (l31 < 16)
        pb = *(const bf16x8*)(sm.u.post.ptb + (((g*4 + h)*16 + l31) << 5) + hi*16);
      const bf16x8 a = *(const bf16x8*)(sm.hBT + xswz(g, mt*32 + l31, hi*16));
      f32x16 acc = ZERO16;
      acc = MFMA32(a, pb, acc, 0, 0, 0);
      if (l31 < 16) {
        const int row = g*16 + l31;
#pragma unroll
        for (int grp = 0; grp < 4; ++grp) {
          const int cb = mt*32 + grp*8 + hi*4;
          const float4 bv = *(const float4*)(bias + cb);
          uint2 o;
          o.x = pk2(fmaxf(acc[grp*4+0] + bv.x, 0.f), fmaxf(acc[grp*4+1] + bv.y, 0.f));
          o.y = pk2(fmaxf(acc[grp*4+2] + bv.z, 0.f), fmaxf(acc[grp*4+3] + bv.w, 0.f));
          *(uint2*)(sm.hA + swz(row, 2*cb)) = o;
        }
      }
    }
  } else {
    const int mt = w & 1;
    f32x16 acc = ZERO16;
#pragma unroll
    for (int h = 0; h < 4; ++h) {                 // chain heads with per-head P
      bf16x8 pb = zero8;
      if (l31 < 16)
        pb = *(const bf16x8*)(sm.u.post.ptb + (((g*4 + h)*16 + l31) << 5) + hi*16);
      const bf16x8 a = *(const bf16x8*)(sm.hBT + xswz(g, h*64 + mt*32 + l31, hi*16));
      acc = MFMA32(a, pb, acc, 0, 0, 0);
    }
    if (l31 < 16) {
      float (*o64)[68] = (float (*)[68])sm.hA;
      const int row = g*16 + l31;
#pragma unroll
      for (int grp = 0; grp < 4; ++grp) {
        const int cb = mt*32 + grp*8 + hi*4;
        const float4 bv = *(const float4*)(bias + cb);
        float4 ov;
        ov.x = fmaf(0.25f, acc[grp*4+0], bv.x);
        ov.y = fmaf(0.25f, acc[grp*4+1], bv.y);
        ov.z = fmaf(0.25f, acc[grp*4+2], bv.z);
        ov.w = fmaf(0.25f, acc[grp*4+3], bv.w);
        *(float4*)&o64[row][cb] = ov;
      }
    }
  }
}

extern "C" __global__ void __launch_bounds__(512, 4)
gat_main(const float* __restrict__ xg, const float* __restrict__ b_in,
         const float* __restrict__ bias0, const float* __restrict__ bias1,
         const float* __restrict__ bias2,
         const uint4* __restrict__ wq0, const uint4* __restrict__ wq1,
         const uint4* __restrict__ wq2, const uint4* __restrict__ winq,
         const float* __restrict__ mw1, const float* __restrict__ mb1,
         const float* __restrict__ g1, const float* __restrict__ be1,
         const u32* __restrict__ mwb2, const float* __restrict__ mb2,
         const float* __restrict__ g2, const float* __restrict__ be2,
         float* __restrict__ out, int Btot)
{
  __shared__ SMem sm;
  const int t = threadIdx.x;
  const int b0 = blockIdx.x * GPB;
  if (b0 >= Btot) return;
  const int lane = t & 63, w = t >> 6;
  const int l31 = lane & 31, hi = lane >> 5;

  // ---- in-proj via MFMA: x loaded straight to B-fragments (waves 0-3) ----
  if (w < 4) {
    const int mtC = w & 1, ntN = w >> 1;
    const int gg = ntN*2 + (l31 >> 4), node = l31 & 15;
    float xv[8];
#pragma unroll
    for (int j = 0; j < 8; ++j)
      xv[j] = xg[(size_t)(b0 + gg)*256 + (hi*8 + j)*16 + node];
    union { u32 uu[4]; bf16x8 v; } bcv;
#pragma unroll
    for (int j = 0; j < 4; ++j) bcv.uu[j] = pk2(xv[2*j], xv[2*j+1]);
    const uint4 aw4 = winq[mtC*64 + lane];
    f32x16 acc = ZERO16;
    acc = MFMA32(*(const bf16x8*)&aw4, bcv.v, acc, 0, 0, 0);
    const int row = ntN*32 + l31;
#pragma unroll
    for (int grp = 0; grp < 4; ++grp) {
      const int cb = mtC*32 + grp*8 + hi*4;
      const float4 bv = *(const float4*)(b_in + cb);
      uint2 o;
      o.x = pk2(fmaxf(acc[grp*4+0] + bv.x, 0.f), fmaxf(acc[grp*4+1] + bv.y, 0.f));
      o.y = pk2(fmaxf(acc[grp*4+2] + bv.z, 0.f), fmaxf(acc[grp*4+3] + bv.w, 0.f));
      *(uint2*)(sm.hA + swz(row, 2*cb)) = o;
    }
  }
  __syncthreads();

  // ---- GAT layers ----
  gemm32<4>(sm, wq0, t);   __syncthreads();
  agg32<0>(sm, bias0, t);  __syncthreads();

  gemm32<16>(sm, wq1, t);  __syncthreads();
  agg32<0>(sm, bias1, t);  __syncthreads();

  gemm32<16>(sm, wq2, t);  __syncthreads();
  agg32<1>(sm, bias2, t);  __syncthreads();

  // ---- global mean pool ----
  if (t < 256) {
    const int g = t >> 6, col = t & 63;
    const float (*o64)[68] = (const float (*)[68])sm.hA;
    float s = 0.f;
#pragma unroll
    for (int r = 0; r < 16; ++r) s += o64[(g << 4) + r][col];
    sm.u.mlp.grs[g][col] = s * (1.f/16.f);
  }
  __syncthreads();

  // ---- MLP1 [64]->[128] ----
  const int mg = t >> 7, o = t & 127;
  float a1v = mb1[o];
#pragma unroll 8
  for (int k = 0; k < 64; ++k) a1v = fmaf(sm.u.mlp.grs[mg][k], mw1[k*128 + o], a1v);
  {
    float su = a1v, sq = a1v*a1v;
#pragma unroll
    for (int off = 32; off >= 1; off >>= 1) { su += __shfl_xor(su, off); sq += __shfl_xor(sq, off); }
    if (lane == 0) { sm.u.mlp.red[0][w][0] = su; sm.u.mlp.red[0][w][1] = sq; }
  }
  __syncthreads();
  {
    const float mu = (sm.u.mlp.red[0][2*mg][0] + sm.u.mlp.red[0][2*mg+1][0]) * (1.f/128.f);
    const float mq = (sm.u.mlp.red[0][2*mg][1] + sm.u.mlp.red[0][2*mg+1][1]) * (1.f/128.f);
    const float rstd = rsqrtf(mq - mu*mu + 1e-5f);
    sm.u.mlp.z1[mg][o] = fmaxf((a1v - mu)*rstd*g1[o] + be1[o], 0.f);
  }
  __syncthreads();

  // ---- MLP2 [128]->[256], LN, relu, store ----
  {
    const float2 bb2 = *(const float2*)(mb2 + 2*o);
    float c0 = bb2.x, c1 = bb2.y;
#pragma unroll 8
    for (int k = 0; k < 128; ++k) {
      const float zk = sm.u.mlp.z1[mg][k];
      const u32 uw = mwb2[k*128 + o];
      c0 = fmaf(zk, __uint_as_float(uw << 16), c0);
      c1 = fmaf(zk, __uint_as_float(uw & 0xffff0000u), c1);
    }
    float su = c0 + c1, sq = c0*c0 + c1*c1;
#pragma unroll
    for (int off = 32; off >= 1; off >>= 1) { su += __shfl_xor(su, off); sq += __shfl_xor(sq, off); }
    if (lane == 0) { sm.u.mlp.red[1][w][0] = su; sm.u.mlp.red[1][w][1] = sq; }
    __syncthreads();
    const float mu = (sm.u.mlp.red[1][2*mg][0] + sm.u.mlp.red[1][2*mg+1][0]) * (1.f/256.f);
    const float mq = (sm.u.mlp.red[1][2*mg][1] + sm.u.mlp.red[1][2*mg+1][1]) * (1.f/256.f);
    const float rstd = rsqrtf(mq - mu*mu + 1e-5f);
    const float2 gg2  = *(const float2*)(g2  + 2*o);
    const float2 bbe2 = *(const float2*)(be2 + 2*o);
    float2 ov;
    ov.x = fmaxf((c0 - mu)*rstd*gg2.x + bbe2.x, 0.f);
    ov.y = fmaxf((c1 - mu)*rstd*gg2.y + bbe2.y, 0.f);
    *(float2*)(out + (size_t)(b0 + mg)*256 + 2*o) = ov;
  }
}

// ---- prepass: 32x32x16 B-fragments (9 n-tiles: 8 cols + fused att) + Win A-frags + mw2 bf16 ----
// u16 layout: wf0 @0 (4*9*512=18432); wf1 @18432 (16*9*512=73728); wf2 @92160 (73728);
//             win @165888 (2*512=1024); mw2 @166912 (32768). total 199680.
__global__ void __launch_bounds__(256)
prep_w(const float* __restrict__ w0, const float* __restrict__ as0, const float* __restrict__ ad0,
       const float* __restrict__ w1, const float* __restrict__ as1, const float* __restrict__ ad1,
       const float* __restrict__ w2, const float* __restrict__ as2, const float* __restrict__ ad2,
       const float* __restrict__ w_in, const float* __restrict__ mw2, u16* __restrict__ wf) {
  const int f = blockIdx.x*256 + threadIdx.x;
  if (f >= 199680) return;
  if (f >= 166912) { wf[f] = (u16)f2bf1(mw2[f - 166912]); return; }
  if (f >= 165888) {
    const int local = f - 165888;
    const int nt = local >> 9, lane = (local >> 3) & 63, j = local & 7;
    wf[f] = (u16)f2bf1(w_in[((lane >> 5)*8 + j)*64 + nt*32 + (lane & 31)]);
    return;
  }
  const float *W, *as_, *ad_; int local;
  if (f < 18432)      { W = w0; as_ = as0; ad_ = ad0; local = f; }
  else if (f < 92160) { W = w1; as_ = as1; ad_ = ad1; local = f - 18432; }
  else                { W = w2; as_ = as2; ad_ = ad2; local = f - 92160; }
  const int ks = local / 4608;
  const int r  = local - ks*4608;
  const int nt = r >> 9;
  const int lane = (r >> 3) & 63;
  const int j = r & 7;
  const int k = ks*16 + (lane >> 5)*8 + j;
  const int col = lane & 31;
  float val;
  if (nt < 8) {
    val = W[k*256 + nt*32 + col];
  } else if (col < 8) {
    const int h = col & 3;
    const float* av = (col < 4) ? as_ : ad_;
    float s = 0.f;
    for (int c = 0; c < 64; ++c) s = fmaf(W[k*256 + h*64 + c], av[h*64 + c], s);
    val = s;
  } else {
    val = 0.f;
  }
  wf[f] = (u16)f2bf1(val);
}

extern "C" void kernel_launch(void* const* d_in, const int* in_sizes, int n_in,
                              void* d_out, int out_size, void* d_ws, size_t ws_size,
                              hipStream_t stream) {
  (void)n_in; (void)out_size; (void)ws_size;
  const float* xg   = (const float*)d_in[0];
  const float* w_in = (const float*)d_in[1];
  const float* b_in = (const float*)d_in[2];
  const float* w0   = (const float*)d_in[3];
  const float* as0  = (const float*)d_in[4];
  const float* ad0  = (const float*)d_in[5];
  const float* bi0  = (const float*)d_in[6];
  const float* w1   = (const float*)d_in[7];
  const float* as1  = (const float*)d_in[8];
  const float* ad1  = (const float*)d_in[9];
  const float* bi1  = (const float*)d_in[10];
  const float* w2   = (const float*)d_in[11];
  const float* as2  = (const float*)d_in[12];
  const float* ad2  = (const float*)d_in[13];
  const float* bi2  = (const float*)d_in[14];
  const float* mw1  = (const float*)d_in[15];
  const float* mb1  = (const float*)d_in[16];
  const float* g1   = (const float*)d_in[17];
  const float* be1  = (const float*)d_in[18];
  const float* mw2  = (const float*)d_in[19];
  const float* mb2  = (const float*)d_in[20];
  const float* g2   = (const float*)d_in[21];
  const float* be2  = (const float*)d_in[22];
  float* out = (float*)d_out;

  const int Btot = in_sizes[0] / 256;               // 8192
  u16* wf = (u16*)d_ws;                             // 199680 u16 = 390 KB
  const uint4* wq0  = (const uint4*)wf;
  const uint4* wq1  = (const uint4*)(wf + 18432);
  const uint4* wq2  = (const uint4*)(wf + 92160);
  const uint4* winq = (const uint4*)(wf + 165888);
  const u32*   mwb2 = (const u32*)(wf + 166912);

  hipLaunchKernelGGL(prep_w, dim3(780), dim3(256), 0, stream,
                     w0, as0, ad0, w1, as1, ad1, w2, as2, ad2, w_in, mw2, wf);

  const int nblocks = (Btot + GPB - 1) / GPB;       // 2048
  hipLaunchKernelGGL(gat_main, dim3(nblocks), dim3(512), 0, stream,
                     xg, b_in, bi0, bi1, bi2, wq0, wq1, wq2, winq,
                     mw1, mb1, g1, be1, mwb2, mb2, g2, be2, out, Btot);
}